// Round 8
// baseline (156.534 us; speedup 1.0000x reference)
//
#include <hip/hip_runtime.h>

// Problem constants (fixed by reference).
#define TT   512
#define BB   2048
#define NTAG 16
#define CH   8              // timesteps staged per chunk
#define NCH  (TT / CH)      // 64 chunks
#define BBN  (BB * NTAG)

typedef float v2f __attribute__((ext_vector_type(2)));

// ---------- DPP helpers ----------
#define DPP_XOR1  0xB1    // quad_perm [1,0,3,2] : lane ^ 1
#define DPP_XOR2  0x4E    // quad_perm [2,3,0,1] : lane ^ 2
#define DPP_XOR3  0x1B    // quad_perm [3,2,1,0] : lane ^ 3
#define DPP_ROR4  0x124   // row_ror:4  : dst lane w gets src w+3 (verified r2)
#define DPP_ROR8  0x128   // +2
#define DPP_ROR12 0x12C   // +1
#define DPP_BC0   0x00    // quad_perm [0,0,0,0] : broadcast quad lane 0
#define DPP_BC1   0x55    // quad_perm [1,1,1,1]
#define DPP_BC2   0xAA    // quad_perm [2,2,2,2]
#define DPP_BC3   0xFF    // quad_perm [3,3,3,3]

template<int CTRL>
__device__ __forceinline__ float dppf(float v) {
    int r = __builtin_amdgcn_update_dpp(0, __builtin_bit_cast(int, v),
                                        CTRL, 0xF, 0xF, true);
    return __builtin_bit_cast(float, r);
}

// Per-component DPP on a packed pair (2 x v_mov_dpp; components independent).
template<int CTRL>
__device__ __forceinline__ v2f dpp2(v2f v) {
    v2f r;
    r.x = dppf<CTRL>(v.x);
    r.y = dppf<CTRL>(v.y);
    return r;
}

#define FMA2(a, b, c) __builtin_elementwise_fma((a), (b), (c))

// 3-wave split, PACKED dual-chain producer (r8):
//   wave 0    : recurrent scan for BOTH 4-elem sets as the two components of
//               v2f state -> v_pk_fma_f32/v_pk_mul_f32 run chain A and B in
//               ONE instruction each. r2 showed interleaved chains fill the
//               ~190cy/step dependency stall but paying 2x scalar issue lost;
//               packed math gives the second chain at ~25% extra issue.
//               Only DPP / v_cos / cndmask double (per-component).
//   waves 1,2 : per set: x staging, accx precompute one chunk ahead (skewed
//               ring, r7), h consume one chunk behind (softmax + store).
// Per-chain FP math is op-for-op identical to the verified r7 kernel (pk ops
// are IEEE f32) -> absmax must be unchanged.
// LDS repack: accx and h rings are v2f[ring][step][lane] so the producer does
// one ds_read_b64 / ds_write_b64 for both chains; consumers read/write their
// float component via cast.
__global__ __launch_bounds__(192, 1) void qlstm_fused(
    const float* __restrict__ x,        // (T,B,8)
    const float* __restrict__ w_gates,  // (4,4,12)
    const float* __restrict__ b_gates,  // (4,4)
    const float* __restrict__ rx_theta, // (4,4)
    const float* __restrict__ w_tag,    // (16,4)
    const float* __restrict__ b_tag,    // (16,)
    float* __restrict__ out)            // (T,B,16)
{
    __shared__ v2f    accV[4][CH][64];      // [ring][step][lane] accx (x=set0,y=set1)
    __shared__ v2f    hrnV[2][CH][64];      // [buf][step][lane]  h    (x=set0,y=set1)
    __shared__ float4 xstg[2][2][64];       // [set][buf][lane]   x staging

    const int tid = threadIdx.x;
    const int wv  = tid >> 6;          // 0 = packed producer; 1,2 = consumers
    const int l   = tid & 63;
    const int e   = l >> 4;

    const float IV  = 0.15915494309189535f;   // 1/(2pi): v_cos takes revolutions
    const float L2E = 1.44269504088896f;
    const float LN2 = 0.69314718056f;

    if (wv == 0) {
        // ==================== producer (dual packed chains) ====================
        const int w = (l >> 2) & 3;             // hidden/wire index (stride 4)
        const int G = l & 3;                    // gate index (in quad)

        // weight row for (gate G, hidden w); h-weights paired with ROR h_{w+j}
        const float* wrow = w_gates + (G * 4 + w) * 12;
        const float wh0 = wrow[8 + ((w + 0) & 3)] * IV;
        const float wh1 = wrow[8 + ((w + 1) & 3)] * IV;
        const float wh2 = wrow[8 + ((w + 2) & 3)] * IV;
        const float wh3 = wrow[8 + ((w + 3) & 3)] * IV;
        const v2f whp0 = { wh0, wh0 }, whp1 = { wh1, wh1 };
        const v2f whp2 = { wh2, wh2 }, whp3 = { wh3, wh3 };

        // Branchless gate activation: odd deg-7 poly act = ab + q*P(q^2).
        // G==2 -> tanh (refit, err<=2e-4); else sigmoid (Taylor, err~2e-5).
        const bool gt = (G == 2);
        const float ab = gt ? 0.0f : 0.5f;
        const float d0 = gt ? 0.999904f  : 0.25f;
        const float d1 = gt ? -0.331065f : -0.0208333333f;
        const float d2 = gt ? 0.120472f  : 0.00208333333f;
        const float d3 = gt ? -0.027717f : -2.10813e-4f;
        const v2f abp = { ab, ab };
        const v2f d0p = { d0, d0 }, d1p = { d1, d1 };
        const v2f d2p = { d2, d2 }, d3p = { d3, d3 };

        // tanh(c) deg-11 odd poly, |c| <= 2.0703 (bounded by construction).
        const v2f u0p = { 0.999160f, 0.999160f };
        const v2f u1p = { -0.325289f, -0.325289f };
        const v2f u2p = { 0.112257f, 0.112257f };
        const v2f u3p = { -0.028766f, -0.028766f };
        const v2f u4p = { 0.0043665f, 0.0043665f };
        const v2f u5p = { -0.00028186f, -0.00028186f };

        const bool w0 = (w == 0), w1 = (w == 1), w3 = (w == 3);

        // accx transposed slot: consumer lane (e, g=G, k=w) = e*16 + G*4 + w
        const int atl = (l & 48) | ((l & 3) << 2) | ((l >> 2) & 3);

        v2f h = { 0.f, 0.f }, c = { 0.f, 0.f };

        __syncthreads();               // P0: accx(0), accx(1) published

        // chunk 0's accx -> regs (latency exposed once, in prologue only)
        v2f a[CH];
        {
            const v2f* ap0 = &accV[0][0][atl];
            #pragma unroll
            for (int i = 0; i < CH; ++i) a[i] = ap0[i * 64];
        }

        for (int cc = 0; cc < NCH; ++cc) {
            // ISSUE next chunk's accx reads now (published at the barrier
            // that started this chunk); first use is after the step loop.
            const v2f* np = &accV[(cc + 1) & 3][0][atl];
            v2f n[CH];
            #pragma unroll
            for (int i = 0; i < CH; ++i) n[i] = np[i * 64];

            v2f* hp = &hrnV[cc & 1][0][l];

            #pragma unroll
            for (int i = 0; i < CH; ++i) {
                // on-chain: h-dot (all DPPs unconditional full-exec)
                const v2f s1 = FMA2(h, whp0, a[i]);
                const v2f s2 = FMA2(dpp2<DPP_ROR12>(h), whp1, s1);
                const v2f mm = dpp2<DPP_ROR8>(h) * whp2;
                const v2f s3 = FMA2(dpp2<DPP_ROR4>(h), whp3, mm);
                const v2f ang = s2 + s3;

                v2f C;
                C.x = __builtin_amdgcn_cosf(ang.x);   // cos(2*pi*ang)
                C.y = __builtin_amdgcn_cosf(ang.y);

                // wire products across w (n_j = C_{w+j}); selects on RESULTS
                // only (r6 lesson: never put a DPP inside a ternary arm).
                // w0: n1*(n2*n3), w1: C*n3, w2: C*(n2*n3), w3: (C*n1)*(n2*n3)
                const v2f n1 = dpp2<DPP_ROR12>(C);
                const v2f n2 = dpp2<DPP_ROR8>(C);
                const v2f n3 = dpp2<DPP_ROR4>(C);
                const v2f Bp = n2 * n3;
                const v2f pp = C * n1;
                const v2f F1  = w0 ? n1 : C;
                const v2f F1b = w3 ? pp : F1;
                const v2f F2  = w1 ? n3 : Bp;
                const v2f q   = F1b * F2;                   // q in [-1,1]

                // gate activation: odd deg-7 poly (valid on ALL lanes)
                const v2f y  = q * q;
                const v2f y2 = y * y;
                const v2f tA = FMA2(y, d1p, d0p);
                const v2f tB = FMA2(y, d3p, d2p);
                const v2f P  = FMA2(y2, tB, tA);
                const v2f act = FMA2(q, P, abp);

                // roles via quad_perm broadcasts (gates live in the quad)
                const v2f A2  = dpp2<DPP_BC2>(act);
                const v2f A12 = dpp2<DPP_BC1>(act) * A2;
                c = FMA2(dpp2<DPP_BC0>(act), c, A12);

                // tanh(c) deg-11 odd poly, distributed form:
                // hr = voc*(t1 + cy2*t4) = fma(voc*cy2, t4, voc*t1)
                const v2f voc = dpp2<DPP_BC3>(act) * c;
                const v2f cy  = c * c;
                const v2f cy2 = cy * cy;
                const v2f t1  = FMA2(cy, u1p, u0p);
                const v2f t2  = FMA2(cy, u3p, u2p);
                const v2f t3  = FMA2(cy, u5p, u4p);
                const v2f t4  = FMA2(cy2, t3, t2);
                const v2f m1v = voc * t1;
                const v2f vc2 = voc * cy2;
                const v2f hr  = FMA2(vc2, t4, m1v);

                // hand off both chains' h in one ds_write_b64
                hp[i * 64] = hr;
                h = hr;
            }

            #pragma unroll
            for (int i = 0; i < CH; ++i) a[i] = n[i];

            __syncthreads();           // publish h(cc); accx(cc+2) now ready
        }
    } else {
        // ============================ consumers ============================
        const int s  = wv - 1;                  // which state set / component
        const int b0 = blockIdx.x * 8 + s * 4;
        const int g  = (l >> 2) & 3;
        const int k  = l & 3;

        const float* wrow = w_gates + (g * 4 + k) * 12;
        // packed x-weights (pairs match ds_read_b128 register adjacency)
        const v2f wp0 = { wrow[0] * IV, wrow[1] * IV };
        const v2f wp1 = { wrow[2] * IV, wrow[3] * IV };
        const v2f wp2 = { wrow[4] * IV, wrow[5] * IV };
        const v2f wp3 = { wrow[6] * IV, wrow[7] * IV };
        const v2f bp  = { (b_gates[g * 4 + k] + rx_theta[g * 4 + k]) * IV, 0.0f };

        // tag weights pre-scaled by log2(e): softmax runs in base 2
        const int tag = g * 4 + k;              // lane owns one output tag
        const float wt0 = w_tag[tag * 4 + (k ^ 0)] * L2E;
        const float wt1 = w_tag[tag * 4 + (k ^ 1)] * L2E;
        const float wt2 = w_tag[tag * 4 + (k ^ 2)] * L2E;
        const float wt3 = w_tag[tag * 4 + (k ^ 3)] * L2E;
        const float bt  = b_tag[tag] * L2E;

        // h slot for (elem e, hidden k): producer lane e*16 + k*4, component s
        const int hsl = e * 16 + k * 4;
        float* outp = out + (size_t)b0 * NTAG + l;   // 64 lanes = 256B per t

        // x staging: lane covers step (l>>3) of each chunk, 16B slot (l&7).
        const float* xlane = x + (size_t)(l >> 3) * (BB * 8)
                               + (size_t)b0 * 8 + (l & 7) * 4;
        const size_t CHOFF = (size_t)CH * BB * 8;

        // accx(m) from x(m) staged in xstg buf (m&1) -> accV ring (m&3), comp s
        auto compute_acc = [&](int xbuf, int ring) {
            float* ap = (float*)&accV[ring][0][l];   // + i*128 floats per step
            #pragma unroll
            for (int i = 0; i < CH; ++i) {
                const float4 xA = xstg[s][xbuf][i * 8 + 2 * e];
                const float4 xB = xstg[s][xbuf][i * 8 + 2 * e + 1];
                const v2f a01 = { xA.x, xA.y }, a23 = { xA.z, xA.w };
                const v2f a45 = { xB.x, xB.y }, a67 = { xB.z, xB.w };
                v2f acc = FMA2(a01, wp0, bp);
                acc = FMA2(a23, wp1, acc);
                acc = FMA2(a45, wp2, acc);
                acc = FMA2(a67, wp3, acc);
                ap[i * 128 + s] = acc.x + acc.y;
            }
        };

        // ---- prologue: x(0),x(1) -> LDS; accx(0),accx(1); x(2) -> LDS ----
        float4 reg = *(const float4*)(xlane);
        xstg[s][0][l] = reg;                         // x0 -> buf0
        reg = *(const float4*)(xlane + CHOFF);
        xstg[s][1][l] = reg;                         // x1 -> buf1
        compute_acc(0, 0);                           // accx(0)
        compute_acc(1, 1);                           // accx(1)
        reg = *(const float4*)(xlane + 2 * CHOFF);
        xstg[s][0][l] = reg;                         // x2 -> buf0 (2&1)
        reg = *(const float4*)(xlane + 3 * CHOFF);   // x(3) in flight
        __syncthreads();               // P0

        for (int cc = 0; cc < NCH; ++cc) {
            const int cur = cc & 1;

            // compute accx(cc+2) from x(cc+2) [buf (cc+2)&1 == cur]
            if (cc + 2 < NCH) compute_acc(cur, (cc + 2) & 3);

            // stage x(cc+3) into buf (cc+3)&1 == cur^1; prefetch x(cc+4)
            if (cc + 3 < NCH) {
                xstg[s][cur ^ 1][l] = reg;
                const int cn = (cc + 4 < NCH) ? cc + 4 : NCH - 1;
                reg = *(const float4*)(xlane + (size_t)cn * CHOFF);
            }

            // consume h(cc-1): projection + log_softmax + store
            if (cc > 0) {
                const float* hpf = (const float*)&hrnV[cur ^ 1][0][hsl];
                #pragma unroll
                for (int i = 0; i < CH; ++i) {
                    // broadcast read (4 g-lanes share one address)
                    const float hv = hpf[i * 128 + s];
                    const float q1 = dppf<DPP_XOR1>(hv);
                    const float q2 = dppf<DPP_XOR2>(hv);
                    const float q3 = dppf<DPP_XOR3>(hv);

                    const float lgq = fmaf(hv, wt0, fmaf(q1, wt1, fmaf(q2, wt2,
                                         fmaf(q3, wt3, bt))));
                    const float ex = __builtin_amdgcn_exp2f(lgq);
                    float sm = ex + dppf<DPP_XOR1>(ex);
                    sm = sm + dppf<DPP_XOR2>(sm);
                    sm = sm + dppf<DPP_ROR4>(sm);
                    sm = sm + dppf<DPP_ROR8>(sm);
                    const float l2s = __builtin_amdgcn_logf(sm);   // log2(s)

                    *outp = (lgq - l2s) * LN2;
                    outp += BBN;
                }
            }
            __syncthreads();
        }

        // epilogue: drain h(63) (buffer 63&1 == 1)
        {
            const float* hpf = (const float*)&hrnV[1][0][hsl];
            #pragma unroll
            for (int i = 0; i < CH; ++i) {
                const float hv = hpf[i * 128 + s];
                const float q1 = dppf<DPP_XOR1>(hv);
                const float q2 = dppf<DPP_XOR2>(hv);
                const float q3 = dppf<DPP_XOR3>(hv);

                const float lgq = fmaf(hv, wt0, fmaf(q1, wt1, fmaf(q2, wt2,
                                     fmaf(q3, wt3, bt))));
                const float ex = __builtin_amdgcn_exp2f(lgq);
                float sm = ex + dppf<DPP_XOR1>(ex);
                sm = sm + dppf<DPP_XOR2>(sm);
                sm = sm + dppf<DPP_ROR4>(sm);
                sm = sm + dppf<DPP_ROR8>(sm);
                const float l2s = __builtin_amdgcn_logf(sm);

                *outp = (lgq - l2s) * LN2;
                outp += BBN;
            }
        }
    }
}

extern "C" void kernel_launch(void* const* d_in, const int* in_sizes, int n_in,
                              void* d_out, int out_size, void* d_ws, size_t ws_size,
                              hipStream_t stream) {
    const float* x        = (const float*)d_in[0];
    const float* w_gates  = (const float*)d_in[1];
    const float* b_gates  = (const float*)d_in[2];
    const float* rx_theta = (const float*)d_in[3];
    const float* w_tag    = (const float*)d_in[4];
    const float* b_tag    = (const float*)d_in[5];
    float* out = (float*)d_out;

    qlstm_fused<<<BB / 8, 192, 0, stream>>>(x, w_gates, b_gates, rx_theta,
                                            w_tag, b_tag, out);
}